// Round 23
// baseline (31.429 us; speedup 1.0000x reference)
//
#include <hip/hip_runtime.h>
#include <hip/hip_bf16.h>

#define BN 4096
#define DD 128

// All five fp8 matrices are pre-scaled by SQS = sqrt(2*log2(e)), so the
// MFMA dot product is directly the exp2 argument: 2^(SQS^2 * dot) = e^(2*dot).
#define SQS 1.69864356f

typedef float f32x4 __attribute__((ext_vector_type(4)));
typedef float f32x2 __attribute__((ext_vector_type(2)));
typedef int   i32x8 __attribute__((ext_vector_type(8)));
typedef int   i32x2 __attribute__((ext_vector_type(2)));

// RAW v_exp_f32 (quarter-rate trans pipe, 1 instruction; guarded builtin
// costs ~5 extra VALU/exp -- r16 vs r17 delta was ~8us).
__device__ __forceinline__ float fast_exp2(float x) {
#if __has_builtin(__builtin_amdgcn_exp2f)
    return __builtin_amdgcn_exp2f(x);
#else
    float r;
    asm("v_exp_f32 %0, %1" : "=v"(r) : "v"(x));
    return r;
#endif
}

// ---------------- prep: f32 -> fp8 e4m3 fragment-major (+gather), diag dots -
// fp8 K=128 fragment layout (self-consistent bijection): per 16-row panel
// (2048 B), lane l's 32 bytes at l*32 hold row (l&15), k = 32*(l>>4)+[0..32).
// Any k-bijection is correct as long as X and Y use the SAME one (MFMA
// reduces over all slots), and our Y-rowsum makes the D row-order moot;
// only D col = lane&15 matters (verified dtype/shape-independent).
__global__ __launch_bounds__(256) void prep_kernel(
    const float* __restrict__ z1, const float* __restrict__ z2,
    const float* __restrict__ attr, const int* __restrict__ uni,
    char* __restrict__ Z1f, char* __restrict__ Z2f,
    char* __restrict__ G1f, char* __restrict__ G2f, char* __restrict__ Af,
    float* __restrict__ d1, float* __restrict__ d2, float* __restrict__ d3,
    float* __restrict__ S1, float* __restrict__ S2, float* __restrict__ out)
{
    int p = blockIdx.x;        // 16-row panel 0..255
    int t = threadIdx.x;       // 0..255
    int gid = p * 256 + t;
    if (gid < 4 * BN) { S1[gid] = 0.f; S2[gid] = 0.f; }
    if (gid == 0) out[0] = 0.f;

    int r = t >> 4, q = t & 15;        // row-in-panel (16), col-eighth (8 f32)
    int grow = p * 16 + r;
    int arow = uni[grow];

    __shared__ float lp[5][16][128];   // SQS-prescaled f32 staging (40 KB)

    const float* sp[5] = { z1 + (size_t)grow * DD, z2 + (size_t)grow * DD,
                           z1 + (size_t)arow * DD, z2 + (size_t)arow * DD,
                           attr + (size_t)arow * DD };
    float v[5][8];
    #pragma unroll
    for (int m = 0; m < 5; m++) {
        const float4* s4 = (const float4*)(sp[m] + q * 8);
        #pragma unroll
        for (int i = 0; i < 2; i++) {
            float4 f = s4[i];
            v[m][4*i+0] = f.x; v[m][4*i+1] = f.y;
            v[m][4*i+2] = f.z; v[m][4*i+3] = f.w;
        }
    }
    float p1 = 0.f, p2 = 0.f, p3 = 0.f;   // diag dots stay f32-exact
    #pragma unroll
    for (int e = 0; e < 8; e++) {
        p3 += v[0][e] * v[1][e];
        p1 += v[2][e] * v[4][e];
        p2 += v[3][e] * v[4][e];
    }
    #pragma unroll
    for (int m = 1; m < 16; m <<= 1) {
        p1 += __shfl_xor(p1, m);
        p2 += __shfl_xor(p2, m);
        p3 += __shfl_xor(p3, m);
    }
    if (q == 0) { d1[grow] = p1; d2[grow] = p2; d3[grow] = p3; }

    #pragma unroll
    for (int m = 0; m < 5; m++)
        #pragma unroll
        for (int e = 0; e < 8; e++)
            lp[m][r][q * 8 + e] = v[m][e] * SQS;
    __syncthreads();

    // Write phase: thread t writes fragment bytes [t*8, t*8+8) of panel p:
    // slot l = t>>2 -> row (t>>2)&15, k0 = 32*(t>>6) + (t&3)*8.
    char* dsts[5] = { Z1f, Z2f, G1f, G2f, Af };
    int rw = (t >> 2) & 15;
    int k0 = 32 * (t >> 6) + (t & 3) * 8;
    #pragma unroll
    for (int m = 0; m < 5; m++) {
        const float* s = &lp[m][rw][k0];
        int w0 = __builtin_amdgcn_cvt_pk_fp8_f32(s[0], s[1], 0, false);
        w0     = __builtin_amdgcn_cvt_pk_fp8_f32(s[2], s[3], w0, true);
        int w1 = __builtin_amdgcn_cvt_pk_fp8_f32(s[4], s[5], 0, false);
        w1     = __builtin_amdgcn_cvt_pk_fp8_f32(s[6], s[7], w1, true);
        i32x2 w = { w0, w1 };
        *reinterpret_cast<i32x2*>(dsts[m] + (size_t)p * 2048 + (size_t)t * 8) = w;
    }
}

// ---------------- sweep: free-running waves, fp8-MX K=128, triple-buffered -
// 6144 equal waves (1536 x 4-wave blocks): each wave owns 64 X-cols (4
// chains x 16, xb 32 regs fp8) and a 256-row Y-chunk = 16 fp8 panels
// (2048 B each) streamed global->reg through yA/yB/yC.  Halved work quantum
// vs r22 (3072 x 512-row): demand 24 waves/CU vs 16 capacity lets the
// dispatcher BACKFILL continuously (CU stays at max residency ~2/3 of the
// kernel instead of draining one lockstep generation); Y L2-traffic is
// unchanged (same chain x panel total).
// mfma_scale_f32_16x16x128_f8f6f4, unit scales (0x7F7F7F7F).  Packed f32x2
// e/e^2 accumulation (v_pk_add/v_pk_fma -- r18: halves accumulate-VALU).
// Swapped operands (A=Y, B=X): D col = lane&15 = X-col; all 16 D-rows
// summed so D row-order and the k-bijection are correctness-irrelevant.
// WRITE_SIZE is the spill tripwire.
__global__ __launch_bounds__(256) void sweep_kernel(
    const char* __restrict__ Z1f, const char* __restrict__ Z2f,
    const char* __restrict__ G1f, const char* __restrict__ G2f,
    const char* __restrict__ Af,
    float* __restrict__ S1, float* __restrict__ S2)
{
    int gwid = blockIdx.x * 4 + (threadIdx.x >> 6);   // 0..6143
    int lane = threadIdx.x & 63;

    int job, xblk, ychunk;
    const char *X, *Y;
    if (gwid < 2048) {            // jobs 0/1: 64 xblk x 16 ychunk (256 rows)
        job = gwid >> 10;
        int rem = gwid & 1023;
        xblk = rem >> 4;          // 0..63
        ychunk = rem & 15;        // 0..15
        X = job ? G2f : G1f;
        Y = Af;
    } else {                      // jobs 2/3: 64 xblk x 32 ychunk (256 rows)
        int g2 = gwid - 2048;
        job = 2 + (g2 >> 11);
        int rem = g2 & 2047;
        xblk = rem >> 5;          // 0..63
        int yc = rem & 31;        // 0..31
        X = (job == 2) ? Z1f : Z2f;
        Y = (yc < 16) ? Z1f : Z2f;
        ychunk = yc & 15;
    }

    size_t laneoff = (size_t)lane * 32;

    // X: 4 chains of 16 cols (B operand), 8 regs each, resident all sweep.
    const char* xp = X + (size_t)(xblk * 4) * 2048 + laneoff;
    i32x8 xb0 = *reinterpret_cast<const i32x8*>(xp);
    i32x8 xb1 = *reinterpret_cast<const i32x8*>(xp + 2048);
    i32x8 xb2 = *reinterpret_cast<const i32x8*>(xp + 4096);
    i32x8 xb3 = *reinterpret_cast<const i32x8*>(xp + 6144);

    // Per-chain packed accumulators (X-col = xblk*64 + chain*16 + (l&15)).
    f32x2 a0e = {0.f,0.f}, a0q = {0.f,0.f}, a1e = {0.f,0.f}, a1q = {0.f,0.f};
    f32x2 a2e = {0.f,0.f}, a2q = {0.f,0.f}, a3e = {0.f,0.f}, a3q = {0.f,0.f};

    i32x8 yA, yB, yC;
    const char* yb0 = Y + (size_t)ychunk * 32768 + laneoff;   // 256 rows

#define LOADY(BUF, PTR) BUF = *reinterpret_cast<const i32x8*>(PTR);

#define COMPY(BUF)                                                           \
    {                                                                        \
        f32x4 c0 = {0.f,0.f,0.f,0.f}, c1 = {0.f,0.f,0.f,0.f};                \
        f32x4 c2 = {0.f,0.f,0.f,0.f}, c3 = {0.f,0.f,0.f,0.f};                \
        c0 = __builtin_amdgcn_mfma_scale_f32_16x16x128_f8f6f4(               \
                 BUF, xb0, c0, 0, 0, 0, 0x7F7F7F7F, 0, 0x7F7F7F7F);          \
        c1 = __builtin_amdgcn_mfma_scale_f32_16x16x128_f8f6f4(               \
                 BUF, xb1, c1, 0, 0, 0, 0x7F7F7F7F, 0, 0x7F7F7F7F);          \
        c2 = __builtin_amdgcn_mfma_scale_f32_16x16x128_f8f6f4(               \
                 BUF, xb2, c2, 0, 0, 0, 0x7F7F7F7F, 0, 0x7F7F7F7F);          \
        c3 = __builtin_amdgcn_mfma_scale_f32_16x16x128_f8f6f4(               \
                 BUF, xb3, c3, 0, 0, 0, 0x7F7F7F7F, 0, 0x7F7F7F7F);          \
        _Pragma("unroll")                                                    \
        for (int q = 0; q < 2; q++) {                                        \
            f32x2 e0 = { fast_exp2(c0[2*q]), fast_exp2(c0[2*q+1]) };         \
            a0e += e0;                                                       \
            a0q = __builtin_elementwise_fma(e0, e0, a0q);                    \
            f32x2 e1 = { fast_exp2(c1[2*q]), fast_exp2(c1[2*q+1]) };         \
            a1e += e1;                                                       \
            a1q = __builtin_elementwise_fma(e1, e1, a1q);                    \
            f32x2 e2 = { fast_exp2(c2[2*q]), fast_exp2(c2[2*q+1]) };         \
            a2e += e2;                                                       \
            a2q = __builtin_elementwise_fma(e2, e2, a2q);                    \
            f32x2 e3 = { fast_exp2(c3[2*q]), fast_exp2(c3[2*q+1]) };         \
            a3e += e3;                                                       \
            a3q = __builtin_elementwise_fma(e3, e3, a3q);                    \
        }                                                                    \
    }

    LOADY(yA, yb0)                         // panel 0
    LOADY(yB, yb0 + 2048)                  // panel 1
    #pragma clang loop unroll(disable)
    for (int it = 0; it < 4; it++) {       // panels 3it .. 3it+2
        const char* pb = yb0 + (size_t)(3 * it) * 2048;
        LOADY(yC, pb + 2 * 2048)           // panel 3it+2
        COMPY(yA)                          // panel 3it
        LOADY(yA, pb + 3 * 2048)           // panel 3it+3
        COMPY(yB)                          // panel 3it+1
        LOADY(yB, pb + 4 * 2048)           // panel 3it+4
        COMPY(yC)                          // panel 3it+2
    }
    // after it=3: computed 0..11, yA = p12, yB = p13
    LOADY(yC, yb0 + 14 * 2048)
    COMPY(yA)                              // panel 12
    LOADY(yA, yb0 + 15 * 2048)
    COMPY(yB)                              // panel 13
    COMPY(yC)                              // panel 14
    COMPY(yA)                              // panel 15
#undef LOADY
#undef COMPY

    // Collapse packed pairs, reduce the 4 lane-groups, commit.
    float r0e = a0e.x + a0e.y, r0q = a0q.x + a0q.y;
    float r1e = a1e.x + a1e.y, r1q = a1q.x + a1q.y;
    float r2e = a2e.x + a2e.y, r2q = a2q.x + a2q.y;
    float r3e = a3e.x + a3e.y, r3q = a3q.x + a3q.y;
    #pragma unroll
    for (int k = 16; k <= 32; k <<= 1) {
        r0e += __shfl_xor(r0e, k); r0q += __shfl_xor(r0q, k);
        r1e += __shfl_xor(r1e, k); r1q += __shfl_xor(r1q, k);
        r2e += __shfl_xor(r2e, k); r2q += __shfl_xor(r2q, k);
        r3e += __shfl_xor(r3e, k); r3q += __shfl_xor(r3q, k);
    }
    if (lane < 16) {
        int base = job * BN + xblk * 64 + lane;
        atomicAdd(&S1[base],      r0e); atomicAdd(&S2[base],      r0q);
        atomicAdd(&S1[base + 16], r1e); atomicAdd(&S2[base + 16], r1q);
        atomicAdd(&S1[base + 32], r2e); atomicAdd(&S2[base + 32], r2q);
        atomicAdd(&S1[base + 48], r3e); atomicAdd(&S2[base + 48], r3q);
    }
}

// ---------------- finalize: per-row loss terms -> weighted mean --------------
__global__ __launch_bounds__(256) void finalize_kernel(
    const float* __restrict__ S1, const float* __restrict__ S2,
    const float* __restrict__ d1, const float* __restrict__ d2,
    const float* __restrict__ d3, float* __restrict__ out)
{
    int idx = blockIdx.x * 256 + threadIdx.x;   // 0..16383
    float term = 0.f;
    const float EM2 = 0.13533528323661270f;     // e^-2
    if (idx < 8192) {                           // inter jobs 0/1
        int j = idx >> 12, i = idx & 4095;
        float dv = j ? d2[i] : d1[i];
        float n = 4095.f;
        float pos = __expf(2.f * dv);
        float s1 = S1[j * BN + i] - pos;
        float s2 = S2[j * BN + i] - pos * pos;
        float rw = s2 * n / s1;
        float ng = (-0.1f * n * pos + rw) * (1.f / 0.9f);
        ng = fmaxf(ng, n * EM2);
        term = logf((pos + ng) / pos) * (0.5f / 4096.f);
    } else {                                    // intra rows 0..8191
        int i = idx - 8192;
        int ii = i & 4095;
        int job = 2 + (i >> 12);
        float n = 8190.f;
        const float E2 = 7.3890560989306495f, E4 = 54.598150033144236f;
        float pos = __expf(2.f * d3[ii]);
        float s1 = S1[job * BN + ii] - E2 - pos;
        float s2 = S2[job * BN + ii] - E4 - pos * pos;
        float rw = s2 * n / s1;
        float ng = (-0.1f * n * pos + rw) * (1.f / 0.9f);
        ng = fmaxf(ng, n * EM2);
        term = logf((pos + ng) / pos) * (1.f / 8192.f);
    }

    #pragma unroll
    for (int m = 1; m < 64; m <<= 1) term += __shfl_xor(term, m);
    __shared__ float sm[4];
    int wid = threadIdx.x >> 6;
    if ((threadIdx.x & 63) == 0) sm[wid] = term;
    __syncthreads();
    if (threadIdx.x == 0) atomicAdd(out, sm[0] + sm[1] + sm[2] + sm[3]);
}

extern "C" void kernel_launch(void* const* d_in, const int* in_sizes, int n_in,
                              void* d_out, int out_size, void* d_ws, size_t ws_size,
                              hipStream_t stream)
{
    const float* z1   = (const float*)d_in[0];
    const float* z2   = (const float*)d_in[1];
    // d_in[2] = text_z : unused by the reference
    const float* attr = (const float*)d_in[3];
    const int*   uni  = (const int*)d_in[4];
    float* out = (float*)d_out;

    char* ws = (char*)d_ws;
    size_t matb = (size_t)BN * DD;                   // bytes per fp8 matrix
    char* Z1f = ws;
    char* Z2f = Z1f + matb;
    char* G1f = Z2f + matb;
    char* G2f = G1f + matb;
    char* Af  = G2f + matb;
    float* S1 = (float*)(ws + 5 * matb);
    float* S2 = S1 + 4 * BN;
    float* d1 = S2 + 4 * BN;
    float* d2 = d1 + BN;
    float* d3 = d2 + BN;

    prep_kernel<<<256, 256, 0, stream>>>(z1, z2, attr, uni,
                                         Z1f, Z2f, G1f, G2f, Af,
                                         d1, d2, d3, S1, S2, out);
    sweep_kernel<<<1536, 256, 0, stream>>>(Z1f, Z2f, G1f, G2f, Af, S1, S2);
    finalize_kernel<<<64, 256, 0, stream>>>(S1, S2, d1, d2, d3, out);
}

// Round 24
// 30.926 us; speedup vs baseline: 1.0162x; 1.0162x over previous
//
#include <hip/hip_runtime.h>
#include <hip/hip_bf16.h>

#define BN 4096
#define DD 128

// All five fp8 matrices are pre-scaled by SQS = sqrt(2*log2(e)), so the
// MFMA dot product is directly the exp2 argument: 2^(SQS^2 * dot) = e^(2*dot).
#define SQS 1.69864356f

typedef float f32x4 __attribute__((ext_vector_type(4)));
typedef float f32x2 __attribute__((ext_vector_type(2)));
typedef int   i32x8 __attribute__((ext_vector_type(8)));
typedef int   i32x2 __attribute__((ext_vector_type(2)));

// RAW v_exp_f32 (quarter-rate trans pipe, 1 instruction; guarded builtin
// costs ~5 extra VALU/exp -- r16 vs r17 delta was ~8us).
__device__ __forceinline__ float fast_exp2(float x) {
#if __has_builtin(__builtin_amdgcn_exp2f)
    return __builtin_amdgcn_exp2f(x);
#else
    float r;
    asm("v_exp_f32 %0, %1" : "=v"(r) : "v"(x));
    return r;
#endif
}

// ---------------- prep: f32 -> fp8 e4m3 fragment-major (+gather), diag dots -
// fp8 K=128 fragment layout (self-consistent bijection): per 16-row panel
// (2048 B), lane l's 32 bytes at l*32 hold row (l&15), k = 32*(l>>4)+[0..32).
// Any k-bijection is correct as long as X and Y use the SAME one (MFMA
// reduces over all slots), and our Y-rowsum makes the D row-order moot;
// only D col = lane&15 matters (verified dtype/shape-independent).
__global__ __launch_bounds__(256) void prep_kernel(
    const float* __restrict__ z1, const float* __restrict__ z2,
    const float* __restrict__ attr, const int* __restrict__ uni,
    char* __restrict__ Z1f, char* __restrict__ Z2f,
    char* __restrict__ G1f, char* __restrict__ G2f, char* __restrict__ Af,
    float* __restrict__ d1, float* __restrict__ d2, float* __restrict__ d3,
    float* __restrict__ S1, float* __restrict__ S2, float* __restrict__ out)
{
    int p = blockIdx.x;        // 16-row panel 0..255
    int t = threadIdx.x;       // 0..255
    int gid = p * 256 + t;
    if (gid < 4 * BN) { S1[gid] = 0.f; S2[gid] = 0.f; }
    if (gid == 0) out[0] = 0.f;

    int r = t >> 4, q = t & 15;        // row-in-panel (16), col-eighth (8 f32)
    int grow = p * 16 + r;
    int arow = uni[grow];

    __shared__ float lp[5][16][128];   // SQS-prescaled f32 staging (40 KB)

    const float* sp[5] = { z1 + (size_t)grow * DD, z2 + (size_t)grow * DD,
                           z1 + (size_t)arow * DD, z2 + (size_t)arow * DD,
                           attr + (size_t)arow * DD };
    float v[5][8];
    #pragma unroll
    for (int m = 0; m < 5; m++) {
        const float4* s4 = (const float4*)(sp[m] + q * 8);
        #pragma unroll
        for (int i = 0; i < 2; i++) {
            float4 f = s4[i];
            v[m][4*i+0] = f.x; v[m][4*i+1] = f.y;
            v[m][4*i+2] = f.z; v[m][4*i+3] = f.w;
        }
    }
    float p1 = 0.f, p2 = 0.f, p3 = 0.f;   // diag dots stay f32-exact
    #pragma unroll
    for (int e = 0; e < 8; e++) {
        p3 += v[0][e] * v[1][e];
        p1 += v[2][e] * v[4][e];
        p2 += v[3][e] * v[4][e];
    }
    #pragma unroll
    for (int m = 1; m < 16; m <<= 1) {
        p1 += __shfl_xor(p1, m);
        p2 += __shfl_xor(p2, m);
        p3 += __shfl_xor(p3, m);
    }
    if (q == 0) { d1[grow] = p1; d2[grow] = p2; d3[grow] = p3; }

    #pragma unroll
    for (int m = 0; m < 5; m++)
        #pragma unroll
        for (int e = 0; e < 8; e++)
            lp[m][r][q * 8 + e] = v[m][e] * SQS;
    __syncthreads();

    // Write phase: thread t writes fragment bytes [t*8, t*8+8) of panel p:
    // slot l = t>>2 -> row (t>>2)&15, k0 = 32*(t>>6) + (t&3)*8.
    char* dsts[5] = { Z1f, Z2f, G1f, G2f, Af };
    int rw = (t >> 2) & 15;
    int k0 = 32 * (t >> 6) + (t & 3) * 8;
    #pragma unroll
    for (int m = 0; m < 5; m++) {
        const float* s = &lp[m][rw][k0];
        int w0 = __builtin_amdgcn_cvt_pk_fp8_f32(s[0], s[1], 0, false);
        w0     = __builtin_amdgcn_cvt_pk_fp8_f32(s[2], s[3], w0, true);
        int w1 = __builtin_amdgcn_cvt_pk_fp8_f32(s[4], s[5], 0, false);
        w1     = __builtin_amdgcn_cvt_pk_fp8_f32(s[6], s[7], w1, true);
        i32x2 w = { w0, w1 };
        *reinterpret_cast<i32x2*>(dsts[m] + (size_t)p * 2048 + (size_t)t * 8) = w;
    }
}

// ---------------- sweep: fp8-MX K=128, MFMA/EXP software stagger ------------
// 6144 equal waves (1536 x 4-wave blocks): each wave owns 64 X-cols (4
// chains x 16, xb 32 regs fp8) and a 256-row Y-chunk = 16 fp8 panels.
// NEW vs r23: explicit 1-deep MFMA/EXP stagger with TWO named accumulator
// sets (p*, q*): step k = { LOAD(k+2) ; MFMA(k+1 -> other set) ; EXP(k <-
// this set) }.  Every MFMA has a full EXP block (~50-80cy trans/VALU)
// between issue and first use, so the matrix-pipe latency hides under the
// trans pipe instead of serializing the wave (r23's COMPY had exp depend
// immediately on the panel's own MFMAs).  Fully unrolled, all names static
// (rule #20); footprint ~115 regs -> 4 waves/SIMD.  WRITE_SIZE = tripwire.
__global__ __launch_bounds__(256) void sweep_kernel(
    const char* __restrict__ Z1f, const char* __restrict__ Z2f,
    const char* __restrict__ G1f, const char* __restrict__ G2f,
    const char* __restrict__ Af,
    float* __restrict__ S1, float* __restrict__ S2)
{
    int gwid = blockIdx.x * 4 + (threadIdx.x >> 6);   // 0..6143
    int lane = threadIdx.x & 63;

    int job, xblk, ychunk;
    const char *X, *Y;
    if (gwid < 2048) {            // jobs 0/1: 64 xblk x 16 ychunk (256 rows)
        job = gwid >> 10;
        int rem = gwid & 1023;
        xblk = rem >> 4;          // 0..63
        ychunk = rem & 15;        // 0..15
        X = job ? G2f : G1f;
        Y = Af;
    } else {                      // jobs 2/3: 64 xblk x 32 ychunk (256 rows)
        int g2 = gwid - 2048;
        job = 2 + (g2 >> 11);
        int rem = g2 & 2047;
        xblk = rem >> 5;          // 0..63
        int yc = rem & 31;        // 0..31
        X = (job == 2) ? Z1f : Z2f;
        Y = (yc < 16) ? Z1f : Z2f;
        ychunk = yc & 15;
    }

    size_t laneoff = (size_t)lane * 32;

    // X: 4 chains of 16 cols (B operand), 8 regs each, resident all sweep.
    const char* xp = X + (size_t)(xblk * 4) * 2048 + laneoff;
    i32x8 xb0 = *reinterpret_cast<const i32x8*>(xp);
    i32x8 xb1 = *reinterpret_cast<const i32x8*>(xp + 2048);
    i32x8 xb2 = *reinterpret_cast<const i32x8*>(xp + 4096);
    i32x8 xb3 = *reinterpret_cast<const i32x8*>(xp + 6144);

    // Per-chain packed accumulators (X-col = xblk*64 + chain*16 + (l&15)).
    f32x2 a0e = {0.f,0.f}, a0q = {0.f,0.f}, a1e = {0.f,0.f}, a1q = {0.f,0.f};
    f32x2 a2e = {0.f,0.f}, a2q = {0.f,0.f}, a3e = {0.f,0.f}, a3q = {0.f,0.f};

    i32x8 yA, yB, yC;
    f32x4 p0, p1, p2, p3, q0, q1, q2, q3;   // two MFMA result sets
    const char* yb0 = Y + (size_t)ychunk * 32768 + laneoff;   // 256 rows

#define LOADY(BUF, IDX) BUF = *reinterpret_cast<const i32x8*>(yb0 + (size_t)(IDX) * 2048);

#define MFMAS(d0, d1, d2, d3, BUF)                                           \
    d0 = __builtin_amdgcn_mfma_scale_f32_16x16x128_f8f6f4(                   \
             BUF, xb0, (f32x4){0.f,0.f,0.f,0.f}, 0,0,0, 0x7F7F7F7F, 0, 0x7F7F7F7F); \
    d1 = __builtin_amdgcn_mfma_scale_f32_16x16x128_f8f6f4(                   \
             BUF, xb1, (f32x4){0.f,0.f,0.f,0.f}, 0,0,0, 0x7F7F7F7F, 0, 0x7F7F7F7F); \
    d2 = __builtin_amdgcn_mfma_scale_f32_16x16x128_f8f6f4(                   \
             BUF, xb2, (f32x4){0.f,0.f,0.f,0.f}, 0,0,0, 0x7F7F7F7F, 0, 0x7F7F7F7F); \
    d3 = __builtin_amdgcn_mfma_scale_f32_16x16x128_f8f6f4(                   \
             BUF, xb3, (f32x4){0.f,0.f,0.f,0.f}, 0,0,0, 0x7F7F7F7F, 0, 0x7F7F7F7F);

#define EXPS(d0, d1, d2, d3)                                                 \
    {                                                                        \
        _Pragma("unroll")                                                    \
        for (int qq = 0; qq < 2; qq++) {                                     \
            f32x2 e0 = { fast_exp2(d0[2*qq]), fast_exp2(d0[2*qq+1]) };       \
            a0e += e0;                                                       \
            a0q = __builtin_elementwise_fma(e0, e0, a0q);                    \
            f32x2 e1 = { fast_exp2(d1[2*qq]), fast_exp2(d1[2*qq+1]) };       \
            a1e += e1;                                                       \
            a1q = __builtin_elementwise_fma(e1, e1, a1q);                    \
            f32x2 e2 = { fast_exp2(d2[2*qq]), fast_exp2(d2[2*qq+1]) };       \
            a2e += e2;                                                       \
            a2q = __builtin_elementwise_fma(e2, e2, a2q);                    \
            f32x2 e3 = { fast_exp2(d3[2*qq]), fast_exp2(d3[2*qq+1]) };       \
            a3e += e3;                                                       \
            a3q = __builtin_elementwise_fma(e3, e3, a3q);                    \
        }                                                                    \
    }

    // Staggered schedule: step k = { LOAD(k+2) ; MFMA(k+1) ; EXP(k) }.
    // Panel n: y-buffer n%3 (A,B,C), c-set n%2 (p,q).
    LOADY(yA, 0)  LOADY(yB, 1)
    MFMAS(p0, p1, p2, p3, yA)                      // M0
    LOADY(yC, 2)   MFMAS(q0, q1, q2, q3, yB)  EXPS(p0, p1, p2, p3)   // E0
    LOADY(yA, 3)   MFMAS(p0, p1, p2, p3, yC)  EXPS(q0, q1, q2, q3)   // E1
    LOADY(yB, 4)   MFMAS(q0, q1, q2, q3, yA)  EXPS(p0, p1, p2, p3)   // E2
    LOADY(yC, 5)   MFMAS(p0, p1, p2, p3, yB)  EXPS(q0, q1, q2, q3)   // E3
    LOADY(yA, 6)   MFMAS(q0, q1, q2, q3, yC)  EXPS(p0, p1, p2, p3)   // E4
    LOADY(yB, 7)   MFMAS(p0, p1, p2, p3, yA)  EXPS(q0, q1, q2, q3)   // E5
    LOADY(yC, 8)   MFMAS(q0, q1, q2, q3, yB)  EXPS(p0, p1, p2, p3)   // E6
    LOADY(yA, 9)   MFMAS(p0, p1, p2, p3, yC)  EXPS(q0, q1, q2, q3)   // E7
    LOADY(yB, 10)  MFMAS(q0, q1, q2, q3, yA)  EXPS(p0, p1, p2, p3)   // E8
    LOADY(yC, 11)  MFMAS(p0, p1, p2, p3, yB)  EXPS(q0, q1, q2, q3)   // E9
    LOADY(yA, 12)  MFMAS(q0, q1, q2, q3, yC)  EXPS(p0, p1, p2, p3)   // E10
    LOADY(yB, 13)  MFMAS(p0, p1, p2, p3, yA)  EXPS(q0, q1, q2, q3)   // E11
    LOADY(yC, 14)  MFMAS(q0, q1, q2, q3, yB)  EXPS(p0, p1, p2, p3)   // E12
    LOADY(yA, 15)  MFMAS(p0, p1, p2, p3, yC)  EXPS(q0, q1, q2, q3)   // E13
    MFMAS(q0, q1, q2, q3, yA)  EXPS(p0, p1, p2, p3)                  // M15,E14
    EXPS(q0, q1, q2, q3)                                             // E15
#undef LOADY
#undef MFMAS
#undef EXPS

    // Collapse packed pairs, reduce the 4 lane-groups, commit.
    float r0e = a0e.x + a0e.y, r0q = a0q.x + a0q.y;
    float r1e = a1e.x + a1e.y, r1q = a1q.x + a1q.y;
    float r2e = a2e.x + a2e.y, r2q = a2q.x + a2q.y;
    float r3e = a3e.x + a3e.y, r3q = a3q.x + a3q.y;
    #pragma unroll
    for (int k = 16; k <= 32; k <<= 1) {
        r0e += __shfl_xor(r0e, k); r0q += __shfl_xor(r0q, k);
        r1e += __shfl_xor(r1e, k); r1q += __shfl_xor(r1q, k);
        r2e += __shfl_xor(r2e, k); r2q += __shfl_xor(r2q, k);
        r3e += __shfl_xor(r3e, k); r3q += __shfl_xor(r3q, k);
    }
    if (lane < 16) {
        int base = job * BN + xblk * 64 + lane;
        atomicAdd(&S1[base],      r0e); atomicAdd(&S2[base],      r0q);
        atomicAdd(&S1[base + 16], r1e); atomicAdd(&S2[base + 16], r1q);
        atomicAdd(&S1[base + 32], r2e); atomicAdd(&S2[base + 32], r2q);
        atomicAdd(&S1[base + 48], r3e); atomicAdd(&S2[base + 48], r3q);
    }
}

// ---------------- finalize: per-row loss terms -> weighted mean --------------
__global__ __launch_bounds__(256) void finalize_kernel(
    const float* __restrict__ S1, const float* __restrict__ S2,
    const float* __restrict__ d1, const float* __restrict__ d2,
    const float* __restrict__ d3, float* __restrict__ out)
{
    int idx = blockIdx.x * 256 + threadIdx.x;   // 0..16383
    float term = 0.f;
    const float EM2 = 0.13533528323661270f;     // e^-2
    if (idx < 8192) {                           // inter jobs 0/1
        int j = idx >> 12, i = idx & 4095;
        float dv = j ? d2[i] : d1[i];
        float n = 4095.f;
        float pos = __expf(2.f * dv);
        float s1 = S1[j * BN + i] - pos;
        float s2 = S2[j * BN + i] - pos * pos;
        float rw = s2 * n / s1;
        float ng = (-0.1f * n * pos + rw) * (1.f / 0.9f);
        ng = fmaxf(ng, n * EM2);
        term = logf((pos + ng) / pos) * (0.5f / 4096.f);
    } else {                                    // intra rows 0..8191
        int i = idx - 8192;
        int ii = i & 4095;
        int job = 2 + (i >> 12);
        float n = 8190.f;
        const float E2 = 7.3890560989306495f, E4 = 54.598150033144236f;
        float pos = __expf(2.f * d3[ii]);
        float s1 = S1[job * BN + ii] - E2 - pos;
        float s2 = S2[job * BN + ii] - E4 - pos * pos;
        float rw = s2 * n / s1;
        float ng = (-0.1f * n * pos + rw) * (1.f / 0.9f);
        ng = fmaxf(ng, n * EM2);
        term = logf((pos + ng) / pos) * (1.f / 8192.f);
    }

    #pragma unroll
    for (int m = 1; m < 64; m <<= 1) term += __shfl_xor(term, m);
    __shared__ float sm[4];
    int wid = threadIdx.x >> 6;
    if ((threadIdx.x & 63) == 0) sm[wid] = term;
    __syncthreads();
    if (threadIdx.x == 0) atomicAdd(out, sm[0] + sm[1] + sm[2] + sm[3]);
}

extern "C" void kernel_launch(void* const* d_in, const int* in_sizes, int n_in,
                              void* d_out, int out_size, void* d_ws, size_t ws_size,
                              hipStream_t stream)
{
    const float* z1   = (const float*)d_in[0];
    const float* z2   = (const float*)d_in[1];
    // d_in[2] = text_z : unused by the reference
    const float* attr = (const float*)d_in[3];
    const int*   uni  = (const int*)d_in[4];
    float* out = (float*)d_out;

    char* ws = (char*)d_ws;
    size_t matb = (size_t)BN * DD;                   // bytes per fp8 matrix
    char* Z1f = ws;
    char* Z2f = Z1f + matb;
    char* G1f = Z2f + matb;
    char* G2f = G1f + matb;
    char* Af  = G2f + matb;
    float* S1 = (float*)(ws + 5 * matb);
    float* S2 = S1 + 4 * BN;
    float* d1 = S2 + 4 * BN;
    float* d2 = d1 + BN;
    float* d3 = d2 + BN;

    prep_kernel<<<256, 256, 0, stream>>>(z1, z2, attr, uni,
                                         Z1f, Z2f, G1f, G2f, Af,
                                         d1, d2, d3, S1, S2, out);
    sweep_kernel<<<1536, 256, 0, stream>>>(Z1f, Z2f, G1f, G2f, Af, S1, S2);
    finalize_kernel<<<64, 256, 0, stream>>>(S1, S2, d1, d2, d3, out);
}